// Round 1
// baseline (631.220 us; speedup 1.0000x reference)
//
#include <hip/hip_runtime.h>
#include <hip/hip_bf16.h>
#include <stdint.h>

#define DI __device__ __forceinline__

typedef __attribute__((ext_vector_type(4))) float f4;
typedef __attribute__((ext_vector_type(4))) float f32x4;
typedef __attribute__((ext_vector_type(4))) unsigned short u16x4;
typedef __attribute__((ext_vector_type(8))) unsigned short u16x8;
typedef __attribute__((ext_vector_type(8))) short s16x8;

static constexpr int BATCH = 16, C = 256, H = 96, W = 96, QK = 64, F = 384;
static constexpr int P = H * W;  // 9216 positions per batch

// ---- workspace layout (bytes) ----
static constexpr size_t SZ_XT  = (size_t)BATCH * P * C * 2;          // 75,497,472
static constexpr size_t OFF_XH = 0;
static constexpr size_t OFF_XL = OFF_XH + SZ_XT;
static constexpr size_t OFF_WH = OFF_XL + SZ_XT;
static constexpr size_t OFF_WL = OFF_WH + (size_t)F * C * 2;
static constexpr size_t OFF_BC = OFF_WL + (size_t)F * C * 2;
static constexpr size_t OFF_QP = OFF_BC + 2048;
static constexpr size_t OFF_KP = OFF_QP + (size_t)BATCH * P * QK * 4;
static constexpr size_t OFF_VP = OFF_KP + (size_t)BATCH * P * QK * 4;
static constexpr size_t OFF_O1 = OFF_VP + (size_t)BATCH * P * C * 2;
static constexpr size_t WS_END = OFF_O1 + (size_t)BATCH * P * C * 2;  // ~378 MB

DI unsigned short f2bf(float f) {
  union { float f; unsigned u; } v; v.f = f;
  unsigned r = v.u + 0x7fffu + ((v.u >> 16) & 1u);
  return (unsigned short)(r >> 16);
}
DI float bf2f(unsigned short b) {
  union { unsigned u; float f; } v; v.u = ((unsigned)b) << 16;
  return v.f;
}

// ---------------- kernel 1: combine + split weights ----------------
__global__ __launch_bounds__(256) void wsplit_kernel(
    const float* __restrict__ Wq, const float* __restrict__ bq,
    const float* __restrict__ Wk, const float* __restrict__ bk,
    const float* __restrict__ Wv, const float* __restrict__ bv,
    unsigned short* __restrict__ wh, unsigned short* __restrict__ wl,
    float* __restrict__ bc) {
  const int f = blockIdx.x;     // 0..383
  const int t = threadIdx.x;    // 0..255 = channel
  const float* src; int row;
  if (f < 64)       { src = Wq; row = f; }
  else if (f < 128) { src = Wk; row = f - 64; }
  else              { src = Wv; row = f - 128; }
  float v = src[row * C + t];
  unsigned short h = f2bf(v);
  wh[f * C + t] = h;
  wl[f * C + t] = f2bf(v - bf2f(h));
  if (t == 0) bc[f] = (f < 64) ? bq[f] : (f < 128) ? bk[f - 64] : bv[f - 128];
}

// ---------------- kernel 2: transpose + split x -> xT[b][p][c] (bf16 hi/lo) ----------------
__global__ __launch_bounds__(256) void prep_kernel(
    const float* __restrict__ x, unsigned short* __restrict__ xh,
    unsigned short* __restrict__ xl) {
  __shared__ float t[64][65];
  const int b = blockIdx.z, c0 = blockIdx.y * 64, p0 = blockIdx.x * 64;
  const int tid = threadIdx.x;
  const float* xb = x + ((size_t)b * C + c0) * P + p0;
#pragma unroll
  for (int pass = 0; pass < 4; ++pass) {
    int cl = pass * 16 + (tid >> 4);
    int p4 = (tid & 15) * 4;
    f4 v = *reinterpret_cast<const f4*>(xb + (size_t)cl * P + p4);
#pragma unroll
    for (int i = 0; i < 4; ++i) t[cl][p4 + i] = v[i];
  }
  __syncthreads();
#pragma unroll
  for (int pass = 0; pass < 2; ++pass) {
    int pl = pass * 32 + (tid >> 3);
    int c8 = (tid & 7) * 8;
    u16x8 hv, lv;
#pragma unroll
    for (int i = 0; i < 8; ++i) {
      float v = t[c8 + i][pl];
      unsigned short h = f2bf(v);
      hv[i] = h;
      lv[i] = f2bf(v - bf2f(h));
    }
    size_t o = ((size_t)b * P + p0 + pl) * C + c0 + c8;
    *reinterpret_cast<u16x8*>(xh + o) = hv;
    *reinterpret_cast<u16x8*>(xl + o) = lv;
  }
}

// ---------------- kernel 3: QKV projection GEMM ----------------
// per batch: out[p][f] = sum_c xT[p][c]*Wcomb[f][c] + bias.  M=9216, N=384, K=256.
// Q/K tiles (nt<2): 3-pass split bf16.  V tiles: 1-pass.
__global__ __launch_bounds__(256) void gemm_qkv(
    const unsigned short* __restrict__ xh, const unsigned short* __restrict__ xl,
    const unsigned short* __restrict__ wh, const unsigned short* __restrict__ wl,
    const float* __restrict__ bc,
    float* __restrict__ Qp, float* __restrict__ Kp, unsigned short* __restrict__ Vp) {
  __shared__ unsigned short Ah[128 * 64], Al[128 * 64], Bh[64 * 64], Bl[64 * 64];
  const int tid = threadIdx.x;
  const int lane = tid & 63;
  const int wv = tid >> 6;
  const int wm = wv >> 1, wn = wv & 1;
  // XCD-chunked swizzle: 6912 blocks = 8 XCDs x 864; n-tiles of one m-tile stay on one XCD.
  const int bid = blockIdx.x;
  const int sw = (bid & 7) * 864 + (bid >> 3);
  const int b = sw / 432;
  const int r = sw - b * 432;
  const int mt = r / 6, nt = r - (r / 6) * 6;
  const int m0 = mt * 128, f0 = nt * 64;
  const bool split = (nt < 2);
  const unsigned short* Abh = xh + (size_t)b * P * C + (size_t)m0 * C;
  const unsigned short* Abl = xl + (size_t)b * P * C + (size_t)m0 * C;

  f32x4 zero = {0.f, 0.f, 0.f, 0.f};
  f32x4 acc[4][2];
#pragma unroll
  for (int i = 0; i < 4; ++i)
#pragma unroll
    for (int j = 0; j < 2; ++j) acc[i][j] = zero;

  const int srow = tid >> 3;  // 0..31
  const int sblk = tid & 7;   // k-block (8 bf16 = 16B)

  for (int k0 = 0; k0 < C; k0 += 64) {
#pragma unroll
    for (int pass = 0; pass < 4; ++pass) {
      int rr = pass * 32 + srow;
      int phys = rr * 64 + ((sblk ^ (rr & 7)) << 3);
      *reinterpret_cast<u16x8*>(&Ah[phys]) =
          *reinterpret_cast<const u16x8*>(Abh + (size_t)rr * C + k0 + sblk * 8);
      if (split)
        *reinterpret_cast<u16x8*>(&Al[phys]) =
            *reinterpret_cast<const u16x8*>(Abl + (size_t)rr * C + k0 + sblk * 8);
    }
#pragma unroll
    for (int pass = 0; pass < 2; ++pass) {
      int rr = pass * 32 + srow;
      int phys = rr * 64 + ((sblk ^ (rr & 7)) << 3);
      *reinterpret_cast<u16x8*>(&Bh[phys]) =
          *reinterpret_cast<const u16x8*>(wh + (size_t)(f0 + rr) * C + k0 + sblk * 8);
      if (split)
        *reinterpret_cast<u16x8*>(&Bl[phys]) =
            *reinterpret_cast<const u16x8*>(wl + (size_t)(f0 + rr) * C + k0 + sblk * 8);
    }
    __syncthreads();
#pragma unroll
    for (int ks = 0; ks < 2; ++ks) {
      const int kb = ks * 4 + (lane >> 4);
      s16x8 a_h[4], a_l[4], b_h[2], b_l[2];
#pragma unroll
      for (int i = 0; i < 4; ++i) {
        int row = wm * 64 + i * 16 + (lane & 15);
        int off = row * 64 + ((kb ^ (row & 7)) << 3);
        a_h[i] = *reinterpret_cast<const s16x8*>(&Ah[off]);
        if (split) a_l[i] = *reinterpret_cast<const s16x8*>(&Al[off]);
      }
#pragma unroll
      for (int j = 0; j < 2; ++j) {
        int row = wn * 32 + j * 16 + (lane & 15);
        int off = row * 64 + ((kb ^ (row & 7)) << 3);
        b_h[j] = *reinterpret_cast<const s16x8*>(&Bh[off]);
        if (split) b_l[j] = *reinterpret_cast<const s16x8*>(&Bl[off]);
      }
#pragma unroll
      for (int i = 0; i < 4; ++i)
#pragma unroll
        for (int j = 0; j < 2; ++j) {
          acc[i][j] = __builtin_amdgcn_mfma_f32_16x16x32_bf16(a_h[i], b_h[j], acc[i][j], 0, 0, 0);
          if (split) {
            acc[i][j] = __builtin_amdgcn_mfma_f32_16x16x32_bf16(a_h[i], b_l[j], acc[i][j], 0, 0, 0);
            acc[i][j] = __builtin_amdgcn_mfma_f32_16x16x32_bf16(a_l[i], b_h[j], acc[i][j], 0, 0, 0);
          }
        }
    }
    __syncthreads();
  }
  // epilogue: add bias, write Q/K fp32 or V bf16
#pragma unroll
  for (int j = 0; j < 2; ++j) {
    int fc = f0 + wn * 32 + j * 16 + (lane & 15);
    float bias = bc[fc];
#pragma unroll
    for (int i = 0; i < 4; ++i) {
#pragma unroll
      for (int q = 0; q < 4; ++q) {
        int p = m0 + wm * 64 + i * 16 + ((lane >> 4) << 2) + q;
        float v = acc[i][j][q] + bias;
        if (nt == 0)      Qp[((size_t)b * P + p) * QK + fc] = v;
        else if (nt == 1) Kp[((size_t)b * P + p) * QK + (fc - 64)] = v;
        else              Vp[((size_t)b * P + p) * C + (fc - 128)] = f2bf(v);
      }
    }
  }
}

// ---------------- kernel 4: column attention, one block per (b,w) ----------------
__global__ __launch_bounds__(256) void attn_kernel(
    const float* __restrict__ Qp, const float* __restrict__ Kp,
    const unsigned short* __restrict__ Vp, unsigned short* __restrict__ O1) {
  __shared__ unsigned short qh[96 * 64], ql[96 * 64], kh[96 * 64], kl[96 * 64];
  __shared__ float sS[96][96];
  __shared__ unsigned short sP[96][104];
  __shared__ unsigned short vt[256][104];
  __shared__ float rsum[96];
  const int tid = threadIdx.x, lane = tid & 63, wv = tid >> 6;
  const int b = blockIdx.x / 96, w = blockIdx.x % 96;

  // ---- stage Q,K (fp32 -> split bf16 hi/lo, XOR-swizzled rows) ----
  {
    const int row16 = tid >> 4;
    const int k4 = (tid & 15) * 4;
    const int kb = k4 >> 3, ko = k4 & 7;
#pragma unroll
    for (int pass = 0; pass < 6; ++pass) {
      int hr = pass * 16 + row16;
      size_t src = ((size_t)b * P + (size_t)hr * 96 + w) * QK + k4;
      f4 qv = *reinterpret_cast<const f4*>(Qp + src);
      f4 kv = *reinterpret_cast<const f4*>(Kp + src);
      int base = hr * 64 + ((kb ^ (hr & 7)) << 3) + ko;
      u16x4 qhv, qlv, khv, klv;
#pragma unroll
      for (int i = 0; i < 4; ++i) {
        float v = qv[i];
        unsigned short hbits = f2bf(v);
        qhv[i] = hbits; qlv[i] = f2bf(v - bf2f(hbits));
        v = kv[i];
        hbits = f2bf(v);
        khv[i] = hbits; klv[i] = f2bf(v - bf2f(hbits));
      }
      *reinterpret_cast<u16x4*>(&qh[base]) = qhv;
      *reinterpret_cast<u16x4*>(&ql[base]) = qlv;
      *reinterpret_cast<u16x4*>(&kh[base]) = khv;
      *reinterpret_cast<u16x4*>(&kl[base]) = klv;
    }
  }
  // ---- stage V transposed: vt[c][g] ----
  {
    const int grow = tid >> 5;
    const int c8 = (tid & 31) * 8;
#pragma unroll
    for (int pass = 0; pass < 12; ++pass) {
      int g = pass * 8 + grow;
      u16x8 v = *reinterpret_cast<const u16x8*>(
          Vp + ((size_t)b * P + (size_t)g * 96 + w) * C + c8);
#pragma unroll
      for (int i = 0; i < 8; ++i) vt[c8 + i][g] = v[i];
    }
  }
  __syncthreads();

  // ---- scores: S[h][g] = sum_q Q[h][q]*K[g][q], 3-pass split MFMA ----
  {
    const int wmq = wv >> 1, wnq = wv & 1;
    f32x4 zero = {0.f, 0.f, 0.f, 0.f};
    f32x4 acc[3][3];
#pragma unroll
    for (int i = 0; i < 3; ++i)
#pragma unroll
      for (int j = 0; j < 3; ++j) acc[i][j] = zero;
#pragma unroll
    for (int ks = 0; ks < 2; ++ks) {
      const int kb = ks * 4 + (lane >> 4);
      s16x8 a_h[3], a_l[3], b_h[3], b_l[3];
#pragma unroll
      for (int i = 0; i < 3; ++i) {
        int row = wmq * 48 + i * 16 + (lane & 15);
        int off = row * 64 + ((kb ^ (row & 7)) << 3);
        a_h[i] = *reinterpret_cast<const s16x8*>(&qh[off]);
        a_l[i] = *reinterpret_cast<const s16x8*>(&ql[off]);
      }
#pragma unroll
      for (int j = 0; j < 3; ++j) {
        int row = wnq * 48 + j * 16 + (lane & 15);
        int off = row * 64 + ((kb ^ (row & 7)) << 3);
        b_h[j] = *reinterpret_cast<const s16x8*>(&kh[off]);
        b_l[j] = *reinterpret_cast<const s16x8*>(&kl[off]);
      }
#pragma unroll
      for (int i = 0; i < 3; ++i)
#pragma unroll
        for (int j = 0; j < 3; ++j) {
          acc[i][j] = __builtin_amdgcn_mfma_f32_16x16x32_bf16(a_h[i], b_h[j], acc[i][j], 0, 0, 0);
          acc[i][j] = __builtin_amdgcn_mfma_f32_16x16x32_bf16(a_h[i], b_l[j], acc[i][j], 0, 0, 0);
          acc[i][j] = __builtin_amdgcn_mfma_f32_16x16x32_bf16(a_l[i], b_h[j], acc[i][j], 0, 0, 0);
        }
    }
#pragma unroll
    for (int i = 0; i < 3; ++i)
#pragma unroll
      for (int j = 0; j < 3; ++j)
#pragma unroll
        for (int q = 0; q < 4; ++q)
          sS[wmq * 48 + i * 16 + ((lane >> 4) << 2) + q][wnq * 48 + j * 16 + (lane & 15)] =
              acc[i][j][q];
  }
  __syncthreads();

  // ---- softmax: 16 groups of 16 lanes, 6 rows each; unnormalized P, deferred 1/sum ----
  {
    const int grp = tid >> 4, l16 = tid & 15;
#pragma unroll
    for (int rr = 0; rr < 6; ++rr) {
      int row = grp * 6 + rr;
      float v[6];
      float m = -1e30f;
#pragma unroll
      for (int j2 = 0; j2 < 6; ++j2) {
        v[j2] = sS[row][l16 + j2 * 16];
        m = fmaxf(m, v[j2]);
      }
#pragma unroll
      for (int o = 8; o >= 1; o >>= 1) m = fmaxf(m, __shfl_xor(m, o, 64));
      float e = 0.f;
#pragma unroll
      for (int j2 = 0; j2 < 6; ++j2) {
        float p = __expf(v[j2] - m);
        e += p;
        sP[row][l16 + j2 * 16] = f2bf(p);
      }
#pragma unroll
      for (int o = 8; o >= 1; o >>= 1) e += __shfl_xor(e, o, 64);
      if (l16 == 0) rsum[row] = 1.0f / e;
    }
  }
  __syncthreads();

  // ---- PV: out[h][c] = sum_g P[h][g] * vt[c][g] ----
  {
    const int wmq = wv >> 1, wnq = wv & 1;
    f32x4 zero = {0.f, 0.f, 0.f, 0.f};
    f32x4 acc[3][8];
#pragma unroll
    for (int i = 0; i < 3; ++i)
#pragma unroll
      for (int j = 0; j < 8; ++j) acc[i][j] = zero;
#pragma unroll
    for (int ks = 0; ks < 3; ++ks) {
      const int kk = ks * 32 + ((lane >> 4) << 3);
      s16x8 a[3];
#pragma unroll
      for (int i = 0; i < 3; ++i)
        a[i] = *reinterpret_cast<const s16x8*>(&sP[wmq * 48 + i * 16 + (lane & 15)][kk]);
#pragma unroll
      for (int j = 0; j < 8; ++j) {
        s16x8 bv = *reinterpret_cast<const s16x8*>(&vt[wnq * 128 + j * 16 + (lane & 15)][kk]);
#pragma unroll
        for (int i = 0; i < 3; ++i)
          acc[i][j] = __builtin_amdgcn_mfma_f32_16x16x32_bf16(a[i], bv, acc[i][j], 0, 0, 0);
      }
    }
    unsigned short* ob = O1 + ((size_t)b * 96 + w) * 96 * C;
#pragma unroll
    for (int i = 0; i < 3; ++i) {
#pragma unroll
      for (int q = 0; q < 4; ++q) {
        int hr = wmq * 48 + i * 16 + ((lane >> 4) << 2) + q;
        float rs = rsum[hr];
#pragma unroll
        for (int j = 0; j < 8; ++j) {
          int c = wnq * 128 + j * 16 + (lane & 15);
          ob[(size_t)hr * C + c] = f2bf(acc[i][j][q] * rs);
        }
      }
    }
  }
}

// ---------------- kernel 5: epilogue transpose + gamma*out + x ----------------
__global__ __launch_bounds__(256) void epi_kernel(
    const unsigned short* __restrict__ O1, const float* __restrict__ x,
    const float* __restrict__ gamma, float* __restrict__ out) {
  __shared__ float t[32][33];
  const int wt = blockIdx.x * 32, ct = blockIdx.y * 32;
  const int bh = blockIdx.z;
  const int b = bh / 96, h = bh % 96;
  const int tid = threadIdx.x;
  {
    int wl = tid >> 3, c4 = (tid & 7) * 4;
    u16x4 v = *reinterpret_cast<const u16x4*>(
        O1 + (((size_t)b * 96 + wt + wl) * 96 + h) * C + ct + c4);
#pragma unroll
    for (int i = 0; i < 4; ++i) t[wl][c4 + i] = bf2f(v[i]);
  }
  __syncthreads();
  const float g = gamma[0];
  {
    int cl = tid >> 3, w4 = (tid & 7) * 4;
    size_t o = (((size_t)b * C + ct + cl) * 96 + h) * 96 + wt + w4;
    f4 xv = *reinterpret_cast<const f4*>(x + o);
    f4 r;
#pragma unroll
    for (int i = 0; i < 4; ++i) r[i] = g * t[w4 + i][cl] + xv[i];
    *reinterpret_cast<f4*>(out + o) = r;
  }
}

extern "C" void kernel_launch(void* const* d_in, const int* in_sizes, int n_in,
                              void* d_out, int out_size, void* d_ws, size_t ws_size,
                              hipStream_t stream) {
  const float* x     = (const float*)d_in[0];
  const float* Wq    = (const float*)d_in[1];
  const float* bq    = (const float*)d_in[2];
  const float* Wk    = (const float*)d_in[3];
  const float* bk    = (const float*)d_in[4];
  const float* Wv    = (const float*)d_in[5];
  const float* bv    = (const float*)d_in[6];
  const float* gamma = (const float*)d_in[7];
  float* out = (float*)d_out;
  char* ws = (char*)d_ws;
  if (ws_size < WS_END) return;  // workspace too small; fail visibly rather than corrupt

  unsigned short* xh = (unsigned short*)(ws + OFF_XH);
  unsigned short* xl = (unsigned short*)(ws + OFF_XL);
  unsigned short* wh = (unsigned short*)(ws + OFF_WH);
  unsigned short* wl = (unsigned short*)(ws + OFF_WL);
  float*          bc = (float*)(ws + OFF_BC);
  float*          Qp = (float*)(ws + OFF_QP);
  float*          Kp = (float*)(ws + OFF_KP);
  unsigned short* Vp = (unsigned short*)(ws + OFF_VP);
  unsigned short* O1 = (unsigned short*)(ws + OFF_O1);

  wsplit_kernel<<<dim3(F), dim3(256), 0, stream>>>(Wq, bq, Wk, bk, Wv, bv, wh, wl, bc);
  prep_kernel<<<dim3(P / 64, C / 64, BATCH), dim3(256), 0, stream>>>(x, xh, xl);
  gemm_qkv<<<dim3(6912), dim3(256), 0, stream>>>(xh, xl, wh, wl, bc, Qp, Kp, Vp);
  attn_kernel<<<dim3(BATCH * 96), dim3(256), 0, stream>>>(Qp, Kp, Vp, O1);
  epi_kernel<<<dim3(3, 8, BATCH * 96), dim3(256), 0, stream>>>(O1, x, gamma, out);
}

// Round 2
// 458.457 us; speedup vs baseline: 1.3768x; 1.3768x over previous
//
#include <hip/hip_runtime.h>
#include <stdint.h>

#define DI __device__ __forceinline__

typedef __attribute__((ext_vector_type(4))) float f4;
typedef __attribute__((ext_vector_type(4))) float f32x4;
typedef __attribute__((ext_vector_type(2))) float f32x2;
typedef _Float16 f16;
typedef __attribute__((ext_vector_type(8))) f16 f16x8;

static constexpr int BATCH = 16, C = 256, H = 96, W = 96, QK = 64, F = 384;
static constexpr int P = H * W;  // 9216

// ---- workspace layout (bytes) ----
static constexpr size_t SZ_XT = (size_t)BATCH * P * C * 2;    // 75,497,472
static constexpr size_t OFF_XT = 0;
static constexpr size_t OFF_WC = OFF_XT + SZ_XT;              // 384*256*2 = 196,608
static constexpr size_t OFF_BC = OFF_WC + (size_t)F * C * 2;
static constexpr size_t OFF_QP = OFF_BC + 4096;               // 16*9216*64*2
static constexpr size_t OFF_KP = OFF_QP + (size_t)BATCH * P * QK * 2;
static constexpr size_t OFF_VP = OFF_KP + (size_t)BATCH * P * QK * 2;
static constexpr size_t OFF_O1 = OFF_VP + (size_t)BATCH * P * C * 2;
static constexpr size_t WS_END = OFF_O1 + (size_t)BATCH * P * C * 2;  // ~265 MB

DI void gll16(const void* g, void* l) {
  // global -> LDS direct copy, 16B per lane; LDS dest = uniform base + lane*16
  __builtin_amdgcn_global_load_lds((const __attribute__((address_space(1))) void*)g,
                                   (__attribute__((address_space(3))) void*)l, 16, 0, 0);
}
DI f32x4 mfma16(f16x8 a, f16x8 b, f32x4 c) {
  return __builtin_amdgcn_mfma_f32_16x16x32_f16(a, b, c, 0, 0, 0);
}

// ---------------- kernel 1: weights -> fp16 [f][c], bias concat ----------------
__global__ __launch_bounds__(256) void wprep_kernel(
    const float* __restrict__ Wq, const float* __restrict__ bq,
    const float* __restrict__ Wk, const float* __restrict__ bk,
    const float* __restrict__ Wv, const float* __restrict__ bv,
    f16* __restrict__ Wc, float* __restrict__ bc) {
  const int f = blockIdx.x, t = threadIdx.x;
  const float* src; int row;
  if (f < 64)       { src = Wq; row = f; }
  else if (f < 128) { src = Wk; row = f - 64; }
  else              { src = Wv; row = f - 128; }
  Wc[f * C + t] = (f16)src[row * C + t];
  if (t == 0) bc[f] = (f < 64) ? bq[f] : (f < 128) ? bk[f - 64] : bv[f - 128];
}

// ---------------- kernel 2: transpose x -> xT[b][p][c] fp16 ----------------
__global__ __launch_bounds__(256) void prep_kernel(const float* __restrict__ x,
                                                   f16* __restrict__ xT) {
  __shared__ float t[64][65];
  const int b = blockIdx.z, c0 = blockIdx.y * 64, p0 = blockIdx.x * 64;
  const int tid = threadIdx.x;
  const float* xb = x + ((size_t)b * C + c0) * P + p0;
#pragma unroll
  for (int pass = 0; pass < 4; ++pass) {
    int cl = pass * 16 + (tid >> 4);
    int p4 = (tid & 15) * 4;
    f4 v = *reinterpret_cast<const f4*>(xb + (size_t)cl * P + p4);
#pragma unroll
    for (int i = 0; i < 4; ++i) t[cl][p4 + i] = v[i];
  }
  __syncthreads();
#pragma unroll
  for (int pass = 0; pass < 2; ++pass) {
    int pl = pass * 32 + (tid >> 3);
    int c8 = (tid & 7) * 8;
    f16x8 hv;
#pragma unroll
    for (int i = 0; i < 8; ++i) hv[i] = (f16)t[c8 + i][pl];
    *reinterpret_cast<f16x8*>(xT + ((size_t)b * P + p0 + pl) * C + c0 + c8) = hv;
  }
}

// ---------------- kernel 3: QKV projection GEMM (fp16 single-pass) ----------------
// out[p][f] = sum_c xT[p][c] * Wc[f][c] + bias. per batch M=9216, N=384, K=256.
// 128x128 tiles: nt=0 -> Q|K (f 0..127), nt=1,2 -> V halves.
__global__ __launch_bounds__(256, 2) void gemm_qkv(
    const f16* __restrict__ xT, const f16* __restrict__ Wc, const float* __restrict__ bc,
    f16* __restrict__ Qp, f16* __restrict__ Kp, f16* __restrict__ Vp) {
  __shared__ f16 As[2][128 * 64];
  __shared__ f16 Bs[2][128 * 64];
  const int tid = threadIdx.x, lane = tid & 63, wv = tid >> 6;
  const int wm = wv >> 1, wn = wv & 1;
  // XCD-chunked swizzle: 3456 = 8 XCD x 432; consecutive chunks share (b,mt) A-slab.
  const int c2 = ((blockIdx.x & 7) * 432) + (blockIdx.x >> 3);
  const int b = c2 / 216;
  const int r = c2 % 216;
  const int mt = r / 3, nt = r % 3;
  const int m0 = mt * 128, f0 = nt * 128;
  const f16* Ab = xT + ((size_t)b * P + m0) * C;
  const f16* Bb = Wc + (size_t)f0 * C;

  const int grow = lane >> 3;              // row within 8-row gll group
  const int lblk = (lane & 7) ^ grow;      // pre-swizzled source 16B block

  f32x4 acc[4][4];
#pragma unroll
  for (int i = 0; i < 4; ++i)
#pragma unroll
    for (int j = 0; j < 4; ++j) acc[i][j] = (f32x4){0.f, 0.f, 0.f, 0.f};

  auto stage = [&](int k0, int bsel) {
#pragma unroll
    for (int s = 0; s < 4; ++s) {
      int rbase = wv * 32 + s * 8;
      int row = rbase + grow;
      gll16(Ab + (size_t)row * C + k0 + lblk * 8, &As[bsel][rbase * 64]);
      gll16(Bb + (size_t)row * C + k0 + lblk * 8, &Bs[bsel][rbase * 64]);
    }
  };
  auto compute = [&](int bsel) {
#pragma unroll
    for (int ks = 0; ks < 2; ++ks) {
      const int kb = ks * 4 + (lane >> 4);
      f16x8 a[4], bb[4];
#pragma unroll
      for (int i = 0; i < 4; ++i) {
        int row = wm * 64 + i * 16 + (lane & 15);
        a[i] = *reinterpret_cast<const f16x8*>(&As[bsel][row * 64 + ((kb ^ (row & 7)) << 3)]);
      }
#pragma unroll
      for (int j = 0; j < 4; ++j) {
        int row = wn * 64 + j * 16 + (lane & 15);
        bb[j] = *reinterpret_cast<const f16x8*>(&Bs[bsel][row * 64 + ((kb ^ (row & 7)) << 3)]);
      }
#pragma unroll
      for (int i = 0; i < 4; ++i)
#pragma unroll
        for (int j = 0; j < 4; ++j) acc[i][j] = mfma16(a[i], bb[j], acc[i][j]);
    }
  };

  stage(0, 0);
  __syncthreads();
  int buf = 0;
#pragma unroll
  for (int t = 0; t < 3; ++t) {
    stage((t + 1) * 64, buf ^ 1);  // issue next-tile loads (stay in flight during MFMA)
    compute(buf);
    __syncthreads();               // vmcnt(0)+barrier: next tile ready
    buf ^= 1;
  }
  compute(buf);

  // epilogue: add bias, direct fp16 stores (32B segments/16 lanes; L2 merges)
#pragma unroll
  for (int j = 0; j < 4; ++j) {
    const int fl = wn * 64 + j * 16 + (lane & 15);  // 0..127 in-tile
    const float bias = bc[f0 + fl];
#pragma unroll
    for (int i = 0; i < 4; ++i) {
#pragma unroll
      for (int q = 0; q < 4; ++q) {
        int p = m0 + wm * 64 + i * 16 + ((lane >> 4) << 2) + q;
        float v = acc[i][j][q] + bias;
        if (nt == 0) {
          if (fl < 64) Qp[((size_t)b * P + p) * QK + fl] = (f16)v;
          else         Kp[((size_t)b * P + p) * QK + (fl - 64)] = (f16)v;
        } else {
          Vp[((size_t)b * P + p) * C + (nt - 1) * 128 + fl] = (f16)v;
        }
      }
    }
  }
}

// ---------------- kernel 4: column attention, one block per (b,w) ----------------
__global__ __launch_bounds__(256, 1) void attn_kernel(
    const f16* __restrict__ Qp, const f16* __restrict__ Kp, const f16* __restrict__ Vp,
    f16* __restrict__ O1) {
  // LDS: qs[96][64] | ks[96][64] | sS[96][100]f32 | vt[256][128] | rsum[96]
  // sP[96][128] overlays qs+ks (dead after scores).
  __shared__ char smem[12288 + 12288 + 38400 + 65536 + 384];
  f16*   qs   = (f16*)smem;
  f16*   ksm  = (f16*)(smem + 12288);
  float* sS   = (float*)(smem + 24576);
  f16*   vt   = (f16*)(smem + 24576 + 38400);
  float* rsum = (float*)(smem + 24576 + 38400 + 65536);
  f16*   sP   = (f16*)smem;

  const int tid = threadIdx.x, lane = tid & 63, wv = tid >> 6;
  const int id = ((blockIdx.x & 7) * 192) + (blockIdx.x >> 3);  // XCD-chunked
  const int b = id / 96, w = id % 96;

  // ---- phase 0: issue V column loads + Q/K global_load_lds, build vt ----
  const int cc = tid;  // each thread owns one channel column of V
  f16 vv[96];
#pragma unroll
  for (int g = 0; g < 96; ++g)
    vv[g] = Vp[((size_t)b * P + g * 96 + w) * C + cc];

  {
    const int grow = lane >> 3;
    const int lblk = (lane & 7) ^ grow;
#pragma unroll
    for (int s = 0; s < 3; ++s) {
      int sec = wv * 3 + s;  // 12 sections of 8 rows
      int row = sec * 8 + grow;
      size_t src = ((size_t)b * P + (size_t)row * 96 + w) * QK + lblk * 8;
      gll16(Qp + src, &qs[sec * 512]);
      gll16(Kp + src, &ksm[sec * 512]);
    }
  }
#pragma unroll
  for (int ob = 0; ob < 12; ++ob) {
    f16x8 pk;
#pragma unroll
    for (int e = 0; e < 8; ++e) pk[e] = vv[ob * 8 + e];
    *reinterpret_cast<f16x8*>(&vt[cc * 128 + ((ob ^ (cc & 15)) << 3)]) = pk;
  }
  __syncthreads();

  // ---- scores: S[h][g] = sum_q Q[h][q] K[g][q] ----
  {
    const int wmq = wv >> 1, wnq = wv & 1;
    f32x4 acc[3][3];
#pragma unroll
    for (int i = 0; i < 3; ++i)
#pragma unroll
      for (int j = 0; j < 3; ++j) acc[i][j] = (f32x4){0.f, 0.f, 0.f, 0.f};
#pragma unroll
    for (int ks = 0; ks < 2; ++ks) {
      const int kb = ks * 4 + (lane >> 4);
      f16x8 a[3], bb[3];
#pragma unroll
      for (int i = 0; i < 3; ++i) {
        int row = wmq * 48 + i * 16 + (lane & 15);
        a[i] = *reinterpret_cast<const f16x8*>(&qs[row * 64 + ((kb ^ (row & 7)) << 3)]);
      }
#pragma unroll
      for (int j = 0; j < 3; ++j) {
        int row = wnq * 48 + j * 16 + (lane & 15);
        bb[j] = *reinterpret_cast<const f16x8*>(&ksm[row * 64 + ((kb ^ (row & 7)) << 3)]);
      }
#pragma unroll
      for (int i = 0; i < 3; ++i)
#pragma unroll
        for (int j = 0; j < 3; ++j) acc[i][j] = mfma16(a[i], bb[j], acc[i][j]);
    }
#pragma unroll
    for (int i = 0; i < 3; ++i)
#pragma unroll
      for (int j = 0; j < 3; ++j)
#pragma unroll
        for (int q = 0; q < 4; ++q)
          sS[(wmq * 48 + i * 16 + ((lane >> 4) << 2) + q) * 100 +
             wnq * 48 + j * 16 + (lane & 15)] = acc[i][j][q];
  }
  __syncthreads();

  // ---- softmax rows (unnormalized P, deferred 1/sum); writes sP (overlays qs/ks) ----
  {
    const int grp = tid >> 4, l16 = tid & 15;
#pragma unroll
    for (int rr = 0; rr < 6; ++rr) {
      const int row = grp * 6 + rr;
      f32x2 v[3];
      float m = -1e30f;
#pragma unroll
      for (int j = 0; j < 3; ++j) {
        v[j] = *reinterpret_cast<const f32x2*>(&sS[row * 100 + 2 * l16 + 32 * j]);
        m = fmaxf(m, fmaxf(v[j][0], v[j][1]));
      }
#pragma unroll
      for (int o = 8; o >= 1; o >>= 1) m = fmaxf(m, __shfl_xor(m, o, 64));
      float e = 0.f;
#pragma unroll
      for (int j = 0; j < 3; ++j) {
        float p0 = __expf(v[j][0] - m), p1 = __expf(v[j][1] - m);
        e += p0 + p1;
        union { unsigned u; f16 h[2]; } pk;
        pk.h[0] = (f16)p0; pk.h[1] = (f16)p1;
        const int gb = (l16 >> 2) + 4 * j;
        *reinterpret_cast<unsigned*>(
            &sP[row * 128 + ((gb ^ (row & 7)) << 3) + 2 * (l16 & 3)]) = pk.u;
      }
#pragma unroll
      for (int o = 8; o >= 1; o >>= 1) e += __shfl_xor(e, o, 64);
      if (l16 == 0) rsum[row] = 1.0f / e;
    }
  }
  __syncthreads();

  // ---- PV: out[h][c] = sum_g P[h][g] vt[c][g] ----
  {
    const int wmq = wv >> 1, wnq = wv & 1;
    f32x4 acc[3][8];
#pragma unroll
    for (int i = 0; i < 3; ++i)
#pragma unroll
      for (int j = 0; j < 8; ++j) acc[i][j] = (f32x4){0.f, 0.f, 0.f, 0.f};
#pragma unroll
    for (int ks = 0; ks < 3; ++ks) {
      const int gb = ks * 4 + (lane >> 4);
      f16x8 a[3];
#pragma unroll
      for (int i = 0; i < 3; ++i) {
        int row = wmq * 48 + i * 16 + (lane & 15);
        a[i] = *reinterpret_cast<const f16x8*>(&sP[row * 128 + ((gb ^ (row & 7)) << 3)]);
      }
#pragma unroll
      for (int j = 0; j < 8; ++j) {
        int crow = wnq * 128 + j * 16 + (lane & 15);
        f16x8 bv = *reinterpret_cast<const f16x8*>(&vt[crow * 128 + ((gb ^ (crow & 15)) << 3)]);
#pragma unroll
        for (int i = 0; i < 3; ++i) acc[i][j] = mfma16(a[i], bv, acc[i][j]);
      }
    }
    f16* ob = O1 + ((size_t)b * 96 + w) * 96 * C;
#pragma unroll
    for (int i = 0; i < 3; ++i) {
#pragma unroll
      for (int q = 0; q < 4; ++q) {
        const int h = wmq * 48 + i * 16 + ((lane >> 4) << 2) + q;
        const float rs = rsum[h];
#pragma unroll
        for (int j = 0; j < 8; ++j) {
          int c = wnq * 128 + j * 16 + (lane & 15);
          ob[(size_t)h * C + c] = (f16)(acc[i][j][q] * rs);
        }
      }
    }
  }
}

// ---------------- kernel 5: epilogue transpose + gamma*out + x ----------------
__global__ __launch_bounds__(256, 3) void epi_kernel(
    const f16* __restrict__ O1, const float* __restrict__ x,
    const float* __restrict__ gamma, float* __restrict__ out) {
  __shared__ f16 t[96 * 256];  // [w][c], 16B blocks swizzled: phys = blk ^ (w&31)
  const int id = ((blockIdx.x & 7) * 192) + (blockIdx.x >> 3);
  const int b = id / 96, h = id % 96;
  const int tid = threadIdx.x, lane = tid & 63, wv = tid >> 6;
  {
    const int grow = lane >> 5;  // row within 2-row gll group
#pragma unroll
    for (int s = 0; s < 12; ++s) {
      int sec = wv * 12 + s;         // 48 sections of 2 rows (512B each)
      int row = sec * 2 + grow;      // w
      int lblk = (lane & 31) ^ (row & 31);
      gll16(O1 + (((size_t)b * 96 + row) * 96 + h) * C + lblk * 8, &t[sec * 512]);
    }
  }
  __syncthreads();
  const float g = gamma[0];
#pragma unroll
  for (int pass = 0; pass < 24; ++pass) {
    const int idx = pass * 256 + tid;
    const int c = idx / 24, wc = idx % 24;
    const int w4 = wc * 4;
    size_t o = (((size_t)b * C + c) * H + h) * W + w4;
    f4 xv = *reinterpret_cast<const f4*>(x + o);
    f4 r;
#pragma unroll
    for (int u = 0; u < 4; ++u) {
      int wr = w4 + u;
      f16 hv = t[wr * 256 + (((c >> 3) ^ (wr & 31)) << 3) + (c & 7)];
      r[u] = g * (float)hv + xv[u];
    }
    *reinterpret_cast<f4*>(out + o) = r;
  }
}

extern "C" void kernel_launch(void* const* d_in, const int* in_sizes, int n_in,
                              void* d_out, int out_size, void* d_ws, size_t ws_size,
                              hipStream_t stream) {
  const float* x     = (const float*)d_in[0];
  const float* Wq    = (const float*)d_in[1];
  const float* bq    = (const float*)d_in[2];
  const float* Wk    = (const float*)d_in[3];
  const float* bk    = (const float*)d_in[4];
  const float* Wv    = (const float*)d_in[5];
  const float* bv    = (const float*)d_in[6];
  const float* gamma = (const float*)d_in[7];
  float* out = (float*)d_out;
  char* ws = (char*)d_ws;
  if (ws_size < WS_END) return;

  f16*   xT = (f16*)(ws + OFF_XT);
  f16*   Wc = (f16*)(ws + OFF_WC);
  float* bc = (float*)(ws + OFF_BC);
  f16*   Qp = (f16*)(ws + OFF_QP);
  f16*   Kp = (f16*)(ws + OFF_KP);
  f16*   Vp = (f16*)(ws + OFF_VP);
  f16*   O1 = (f16*)(ws + OFF_O1);

  wprep_kernel<<<dim3(F), dim3(256), 0, stream>>>(Wq, bq, Wk, bk, Wv, bv, Wc, bc);
  prep_kernel<<<dim3(P / 64, C / 64, BATCH), dim3(256), 0, stream>>>(x, xT);
  gemm_qkv<<<dim3(3456), dim3(256), 0, stream>>>(xT, Wc, bc, Qp, Kp, Vp);
  attn_kernel<<<dim3(BATCH * 96), dim3(256), 0, stream>>>(Qp, Kp, Vp, O1);
  epi_kernel<<<dim3(BATCH * 96), dim3(256), 0, stream>>>(O1, x, gamma, out);
}

// Round 3
// 425.038 us; speedup vs baseline: 1.4851x; 1.0786x over previous
//
#include <hip/hip_runtime.h>
#include <stdint.h>

#define DI __device__ __forceinline__

typedef __attribute__((ext_vector_type(4))) float f4;
typedef __attribute__((ext_vector_type(4))) float f32x4;
typedef _Float16 f16;
typedef __attribute__((ext_vector_type(8))) f16 f16x8;

static constexpr int BATCH = 16, C = 256, H = 96, W = 96, QK = 64, F = 384;
static constexpr int P = H * W;  // 9216

// ---- workspace layout (bytes) ----
static constexpr size_t OFF_WC = 0;                                    // 384*256*2
static constexpr size_t OFF_BC = OFF_WC + (size_t)F * C * 2;
static constexpr size_t OFF_QP = OFF_BC + 4096;
static constexpr size_t OFF_KP = OFF_QP + (size_t)BATCH * P * QK * 2;  // 18.9 MB each
static constexpr size_t OFF_VP = OFF_KP + (size_t)BATCH * P * QK * 2;
static constexpr size_t OFF_O1 = OFF_VP + (size_t)BATCH * P * C * 2;   // 75.5 MB
static constexpr size_t WS_END = OFF_O1 + (size_t)BATCH * P * C * 2;   // ~189 MB

DI void gll16(const void* g, void* l) {
  __builtin_amdgcn_global_load_lds((const __attribute__((address_space(1))) void*)g,
                                   (__attribute__((address_space(3))) void*)l, 16, 0, 0);
}
DI f32x4 mfma16(f16x8 a, f16x8 b, f32x4 c) {
  return __builtin_amdgcn_mfma_f32_16x16x32_f16(a, b, c, 0, 0, 0);
}
DI int mod13(int v) {  // valid for 0..6553
  return v - 13 * ((v * 5042) >> 16);
}

// ---------------- kernel 1: weights -> fp16 [f][c], bias concat ----------------
__global__ __launch_bounds__(256) void wprep_kernel(
    const float* __restrict__ Wq, const float* __restrict__ bq,
    const float* __restrict__ Wk, const float* __restrict__ bk,
    const float* __restrict__ Wv, const float* __restrict__ bv,
    f16* __restrict__ Wc, float* __restrict__ bc) {
  const int f = blockIdx.x, t = threadIdx.x;
  const float* src; int row;
  if (f < 64)       { src = Wq; row = f; }
  else if (f < 128) { src = Wk; row = f - 64; }
  else              { src = Wv; row = f - 128; }
  Wc[f * C + t] = (f16)src[row * C + t];
  if (t == 0) bc[f] = (f < 64) ? bq[f] : (f < 128) ? bk[f - 64] : bv[f - 128];
}

// ---------------- kernel 2: QKV GEMM with fused transpose+convert ----------------
// out[p][f] = sum_c x[b][c][p] * Wc[f][c] + bias.  M=9216, N=384, K=256.
// A staged from fp32 x via regs -> fp16 LDS [128][72] (pad-72: conflict-free, no xor).
__global__ __launch_bounds__(256, 2) void gemm_qkv(
    const float* __restrict__ x, const f16* __restrict__ Wc, const float* __restrict__ bc,
    f16* __restrict__ Qp, f16* __restrict__ Kp, f16* __restrict__ Vp) {
  __shared__ f16 As[2][128 * 72];
  __shared__ f16 Bs[2][128 * 64];
  const int tid = threadIdx.x, lane = tid & 63, wv = tid >> 6;
  const int wm = wv >> 1, wn = wv & 1;
  // XCD-chunked swizzle: 3456 = 8 XCD x 432; consecutive chunks share (b,mt) A-slab.
  const int c2 = ((blockIdx.x & 7) * 432) + (blockIdx.x >> 3);
  const int b = c2 / 216, r = c2 % 216;
  const int mt = r / 3, nt = r % 3;
  const int m0 = mt * 128, f0 = nt * 128;
  const float* Ax = x + (size_t)b * C * P + m0;
  const f16* Bb = Wc + (size_t)f0 * C;

  const int ap = tid & 127;   // p within tile
  const int ach = tid >> 7;   // 0..1 (c-octet phase)
  const int grow = lane >> 3, lblk = (lane & 7) ^ grow;

  f32x4 acc[4][4];
#pragma unroll
  for (int i = 0; i < 4; ++i)
#pragma unroll
    for (int j = 0; j < 4; ++j) acc[i][j] = (f32x4){0.f, 0.f, 0.f, 0.f};

  float av[4][8];
  auto loadA = [&](int k0) {
#pragma unroll
    for (int s = 0; s < 4; ++s) {
      const int c = k0 + (s * 2 + ach) * 8;
#pragma unroll
      for (int u = 0; u < 8; ++u) av[s][u] = Ax[(size_t)(c + u) * P + ap];
    }
  };
  auto writeA = [&](int bsel) {
#pragma unroll
    for (int s = 0; s < 4; ++s) {
      const int cb = s * 2 + ach;
      f16x8 hv;
#pragma unroll
      for (int u = 0; u < 8; ++u) hv[u] = (f16)av[s][u];
      *reinterpret_cast<f16x8*>(&As[bsel][ap * 72 + cb * 8]) = hv;
    }
  };
  auto stageB = [&](int k0, int bsel) {
#pragma unroll
    for (int s = 0; s < 4; ++s) {
      const int rbase = wv * 32 + s * 8;
      gll16(Bb + (size_t)(rbase + grow) * C + k0 + lblk * 8, &Bs[bsel][rbase * 64]);
    }
  };
  auto compute = [&](int bsel) {
#pragma unroll
    for (int ks = 0; ks < 2; ++ks) {
      const int kb = ks * 4 + (lane >> 4);
      f16x8 a[4], bb[4];
#pragma unroll
      for (int i = 0; i < 4; ++i) {
        const int row = wm * 64 + i * 16 + (lane & 15);
        a[i] = *reinterpret_cast<const f16x8*>(&As[bsel][row * 72 + kb * 8]);
      }
#pragma unroll
      for (int j = 0; j < 4; ++j) {
        const int row = wn * 64 + j * 16 + (lane & 15);
        bb[j] = *reinterpret_cast<const f16x8*>(&Bs[bsel][row * 64 + ((kb ^ (row & 7)) << 3)]);
      }
#pragma unroll
      for (int i = 0; i < 4; ++i)
#pragma unroll
        for (int j = 0; j < 4; ++j) acc[i][j] = mfma16(a[i], bb[j], acc[i][j]);
    }
  };

  loadA(0);
  stageB(0, 0);
  writeA(0);
  __syncthreads();
  int buf = 0;
#pragma unroll
  for (int t = 0; t < 3; ++t) {
    loadA((t + 1) * 64);        // issue next-tile A loads (hidden under compute)
    stageB((t + 1) * 64, buf ^ 1);
    compute(buf);
    writeA(buf ^ 1);            // vmcnt naturally waits here, after compute
    __syncthreads();
    buf ^= 1;
  }
  compute(buf);

  // epilogue: add bias, fp16 stores
#pragma unroll
  for (int j = 0; j < 4; ++j) {
    const int fl = wn * 64 + j * 16 + (lane & 15);
    const float bias = bc[f0 + fl];
#pragma unroll
    for (int i = 0; i < 4; ++i) {
#pragma unroll
      for (int q = 0; q < 4; ++q) {
        const int p = m0 + wm * 64 + i * 16 + ((lane >> 4) << 2) + q;
        const float v = acc[i][j][q] + bias;
        if (nt == 0) {
          if (fl < 64) Qp[((size_t)b * P + p) * QK + fl] = (f16)v;
          else         Kp[((size_t)b * P + p) * QK + (fl - 64)] = (f16)v;
        } else {
          Vp[((size_t)b * P + p) * C + (nt - 1) * 128 + fl] = (f16)v;
        }
      }
    }
  }
}

// ---------------- kernel 3: column attention, one block per (b,w), 2 blocks/CU ----------------
// LDS 77.5 KB: qs[96][64] | ks[96][64] (sP[96][128] overlays both) | vt[256][104] rot13 | red[2x2][96]
__global__ __launch_bounds__(256, 2) void attn_kernel(
    const f16* __restrict__ Qp, const f16* __restrict__ Kp, const f16* __restrict__ Vp,
    f16* __restrict__ O1) {
  __shared__ char smem[24576 + 53248 + 768 + 768];
  f16*   qs   = (f16*)smem;                    // [96][64] xor-swz rows
  f16*   ksm  = (f16*)(smem + 12288);
  f16*   sP   = (f16*)smem;                    // overlays qs+ks after scores
  f16*   vt   = (f16*)(smem + 24576);          // [256][104] mod-13 rotated 16B blocks
  float* redm = (float*)(smem + 24576 + 53248);  // [2][96] cross-wave max
  float* reds = redm + 192;                      // [2][96] cross-wave sum

  const int tid = threadIdx.x, lane = tid & 63, wv = tid >> 6;
  const int wmq = wv >> 1, wnq = wv & 1;
  const int id = ((blockIdx.x & 7) * 192) + (blockIdx.x >> 3);  // XCD-chunked
  const int b = id / 96, w = id % 96;

  // ---- phase 0: V column loads (reg transpose) + Q/K global_load_lds ----
  const int cc = tid;
  f16 vv[96];
#pragma unroll
  for (int g = 0; g < 96; ++g)
    vv[g] = Vp[((size_t)b * P + g * 96 + w) * C + cc];

  {
    const int grow = lane >> 3;
    const int lblk = (lane & 7) ^ grow;
#pragma unroll
    for (int s = 0; s < 3; ++s) {
      const int sec = wv * 3 + s;
      const int row = sec * 8 + grow;
      const size_t src = ((size_t)b * P + (size_t)row * 96 + w) * QK + lblk * 8;
      gll16(Qp + src, &qs[sec * 512]);
      gll16(Kp + src, &ksm[sec * 512]);
    }
  }
  {
    const int r13 = mod13(cc);
#pragma unroll
    for (int ob = 0; ob < 12; ++ob) {
      int phys = ob + r13;
      if (phys >= 13) phys -= 13;
      f16x8 pk;
#pragma unroll
      for (int e = 0; e < 8; ++e) pk[e] = vv[ob * 8 + e];
      *reinterpret_cast<f16x8*>(&vt[cc * 104 + phys * 8]) = pk;
    }
  }
  __syncthreads();

  // ---- scores in registers: S[h][g] = sum_q Q[h][q] K[g][q] ----
  f32x4 acc[3][3];
#pragma unroll
  for (int i = 0; i < 3; ++i)
#pragma unroll
    for (int j = 0; j < 3; ++j) acc[i][j] = (f32x4){0.f, 0.f, 0.f, 0.f};
#pragma unroll
  for (int ks = 0; ks < 2; ++ks) {
    const int kb = ks * 4 + (lane >> 4);
    f16x8 a[3], bb[3];
#pragma unroll
    for (int i = 0; i < 3; ++i) {
      const int row = wmq * 48 + i * 16 + (lane & 15);
      a[i] = *reinterpret_cast<const f16x8*>(&qs[row * 64 + ((kb ^ (row & 7)) << 3)]);
    }
#pragma unroll
    for (int j = 0; j < 3; ++j) {
      const int row = wnq * 48 + j * 16 + (lane & 15);
      bb[j] = *reinterpret_cast<const f16x8*>(&ksm[row * 64 + ((kb ^ (row & 7)) << 3)]);
    }
#pragma unroll
    for (int i = 0; i < 3; ++i)
#pragma unroll
      for (int j = 0; j < 3; ++j) acc[i][j] = mfma16(a[i], bb[j], acc[i][j]);
  }

  // ---- register softmax: C-frag row h = wmq*48+i*16+(lane>>4)*4+q, col g = wnq*48+j*16+(lane&15) ----
#pragma unroll
  for (int i = 0; i < 3; ++i)
#pragma unroll
    for (int q = 0; q < 4; ++q) {
      float m = fmaxf(fmaxf(acc[i][0][q], acc[i][1][q]), acc[i][2][q]);
#pragma unroll
      for (int o = 8; o >= 1; o >>= 1) m = fmaxf(m, __shfl_xor(m, o, 64));
      if ((lane & 15) == 0)
        redm[wnq * 96 + wmq * 48 + i * 16 + ((lane >> 4) << 2) + q] = m;
    }
  __syncthreads();  // also frees qs/ks for sP overlay
#pragma unroll
  for (int i = 0; i < 3; ++i)
#pragma unroll
    for (int q = 0; q < 4; ++q) {
      const int h = wmq * 48 + i * 16 + ((lane >> 4) << 2) + q;
      const float m = fmaxf(redm[h], redm[96 + h]);
      float s = 0.f;
#pragma unroll
      for (int j = 0; j < 3; ++j) {
        const float p = __expf(acc[i][j][q] - m);
        acc[i][j][q] = p;
        s += p;
      }
#pragma unroll
      for (int o = 8; o >= 1; o >>= 1) s += __shfl_xor(s, o, 64);
      if ((lane & 15) == 0) reds[wnq * 96 + h] = s;
    }
  // unnormalized P -> sP fp16 (xor-swizzled rows)
#pragma unroll
  for (int i = 0; i < 3; ++i)
#pragma unroll
    for (int q = 0; q < 4; ++q) {
      const int h = wmq * 48 + i * 16 + ((lane >> 4) << 2) + q;
#pragma unroll
      for (int j = 0; j < 3; ++j) {
        const int g = wnq * 48 + j * 16 + (lane & 15);
        sP[h * 128 + (((g >> 3) ^ (h & 7)) << 3) + (g & 7)] = (f16)acc[i][j][q];
      }
    }
  __syncthreads();

  // ---- PV: out[h][c] = sum_g P[h][g] vt[c][g]; deferred 1/sum ----
  {
    f32x4 o[3][8];
#pragma unroll
    for (int i = 0; i < 3; ++i)
#pragma unroll
      for (int j = 0; j < 8; ++j) o[i][j] = (f32x4){0.f, 0.f, 0.f, 0.f};
#pragma unroll
    for (int ks = 0; ks < 3; ++ks) {
      const int gb = ks * 4 + (lane >> 4);
      f16x8 a[3];
#pragma unroll
      for (int i = 0; i < 3; ++i) {
        const int row = wmq * 48 + i * 16 + (lane & 15);
        a[i] = *reinterpret_cast<const f16x8*>(&sP[row * 128 + ((gb ^ (row & 7)) << 3)]);
      }
#pragma unroll
      for (int j = 0; j < 8; ++j) {
        const int crow = wnq * 128 + j * 16 + (lane & 15);
        int phys = gb + mod13(crow);
        if (phys >= 13) phys -= 13;
        const f16x8 bv = *reinterpret_cast<const f16x8*>(&vt[crow * 104 + phys * 8]);
#pragma unroll
        for (int i = 0; i < 3; ++i) o[i][j] = mfma16(a[i], bv, o[i][j]);
      }
    }
    f16* ob_ = O1 + ((size_t)b * 96 + w) * 96 * C;
#pragma unroll
    for (int i = 0; i < 3; ++i) {
#pragma unroll
      for (int q = 0; q < 4; ++q) {
        const int h = wmq * 48 + i * 16 + ((lane >> 4) << 2) + q;
        const float rs = 1.0f / (reds[h] + reds[96 + h]);
#pragma unroll
        for (int j = 0; j < 8; ++j) {
          const int c = wnq * 128 + j * 16 + (lane & 15);
          ob_[(size_t)h * C + c] = (f16)(o[i][j][q] * rs);
        }
      }
    }
  }
}

// ---------------- kernel 4: epilogue transpose + gamma*out + x ----------------
__global__ __launch_bounds__(256, 3) void epi_kernel(
    const f16* __restrict__ O1, const float* __restrict__ x,
    const float* __restrict__ gamma, float* __restrict__ out) {
  __shared__ f16 t[96 * 256];  // [w][c], 16B blocks swizzled: phys = blk ^ (w&31)
  const int id = ((blockIdx.x & 7) * 192) + (blockIdx.x >> 3);
  const int b = id / 96, h = id % 96;
  const int tid = threadIdx.x, lane = tid & 63, wv = tid >> 6;
  {
    const int grow = lane >> 5;
#pragma unroll
    for (int s = 0; s < 12; ++s) {
      const int sec = wv * 12 + s;
      const int row = sec * 2 + grow;
      const int lblk = (lane & 31) ^ (row & 31);
      gll16(O1 + (((size_t)b * 96 + row) * 96 + h) * C + lblk * 8, &t[sec * 512]);
    }
  }
  __syncthreads();
  const float g = gamma[0];
#pragma unroll
  for (int pass = 0; pass < 24; ++pass) {
    const int idx = pass * 256 + tid;
    const int c = idx / 24, wc = idx % 24;
    const int w4 = wc * 4;
    const size_t o = (((size_t)b * C + c) * H + h) * W + w4;
    const f4 xv = *reinterpret_cast<const f4*>(x + o);
    f4 r;
#pragma unroll
    for (int u = 0; u < 4; ++u) {
      const int wr = w4 + u;
      const f16 hv = t[wr * 256 + (((c >> 3) ^ (wr & 31)) << 3) + (c & 7)];
      r[u] = g * (float)hv + xv[u];
    }
    *reinterpret_cast<f4*>(out + o) = r;
  }
}

extern "C" void kernel_launch(void* const* d_in, const int* in_sizes, int n_in,
                              void* d_out, int out_size, void* d_ws, size_t ws_size,
                              hipStream_t stream) {
  const float* x     = (const float*)d_in[0];
  const float* Wq    = (const float*)d_in[1];
  const float* bq    = (const float*)d_in[2];
  const float* Wk    = (const float*)d_in[3];
  const float* bk    = (const float*)d_in[4];
  const float* Wv    = (const float*)d_in[5];
  const float* bv    = (const float*)d_in[6];
  const float* gamma = (const float*)d_in[7];
  float* out = (float*)d_out;
  char* ws = (char*)d_ws;
  if (ws_size < WS_END) return;

  f16*   Wc = (f16*)(ws + OFF_WC);
  float* bc = (float*)(ws + OFF_BC);
  f16*   Qp = (f16*)(ws + OFF_QP);
  f16*   Kp = (f16*)(ws + OFF_KP);
  f16*   Vp = (f16*)(ws + OFF_VP);
  f16*   O1 = (f16*)(ws + OFF_O1);

  wprep_kernel<<<dim3(F), dim3(256), 0, stream>>>(Wq, bq, Wk, bk, Wv, bv, Wc, bc);
  gemm_qkv<<<dim3(3456), dim3(256), 0, stream>>>(x, Wc, bc, Qp, Kp, Vp);
  attn_kernel<<<dim3(BATCH * 96), dim3(256), 0, stream>>>(Qp, Kp, Vp, O1);
  epi_kernel<<<dim3(BATCH * 96), dim3(256), 0, stream>>>(O1, x, gamma, out);
}